// Round 1
// baseline (8978.003 us; speedup 1.0000x reference)
//
#include <hip/hip_runtime.h>
#include <float.h>

// FPS: N=524288 points, select M=2048 indices (idx[0]=0), output pos[idxs] (2048x3 f32).
// Persistent cooperative kernel; per-thread point data in registers; one grid
// barrier per selected point via hand-rolled monotone-counter barrier.

#define NPTS     524288
#define MOUT     2048
#define NBLK     64
#define NTHR     1024
#define NWAVE    (NTHR / 64)
#define GTHREADS (NBLK * NTHR)
#define PPT      (NPTS / GTHREADS)   // 8 points per thread

__device__ __forceinline__ unsigned long long packvi(float v, unsigned idx) {
    // min_d >= 0 always, so IEEE bit pattern order == value order.
    // Inverted index: among equal values, larger (0xFFFFFFFF - idx) == smaller idx wins
    // => matches jnp.argmax first-occurrence semantics at every reduction level.
    return ((unsigned long long)__float_as_uint(v) << 32) |
           (unsigned long long)(0xFFFFFFFFu - idx);
}

__global__ void __launch_bounds__(NTHR, 1) fps_kernel(
    const float* __restrict__ pos, float* __restrict__ out,
    unsigned long long* __restrict__ slots, unsigned* __restrict__ cnt)
{
    const unsigned tid = threadIdx.x;
    const unsigned g   = blockIdx.x * NTHR + tid;

    // Register-resident points + running min squared distance.
    float X[PPT], Y[PPT], Z[PPT], D[PPT];
#pragma unroll
    for (int p = 0; p < PPT; ++p) {
        const unsigned idx = g + (unsigned)p * GTHREADS;
        X[p] = pos[3u * idx + 0];
        Y[p] = pos[3u * idx + 1];
        Z[p] = pos[3u * idx + 2];
        D[p] = FLT_MAX;
    }

    // idxs[0] = 0 deterministically.
    float px = pos[0], py = pos[1], pz = pos[2];
    if (blockIdx.x == 0 && tid == 0) {
        out[0] = px; out[1] = py; out[2] = pz;
    }

    __shared__ unsigned long long sred[NWAVE];
    __shared__ float sx, sy, sz;

    unsigned target = NBLK;

    for (int i = 1; i < MOUT; ++i) {
        // ---- distance update + per-thread argmax (exact fp32, no FMA contraction,
        // ---- sum order (dx^2+dy^2)+dz^2 to match numpy/jnp) ----
        float bv = -1.0f;       // all min_d >= 0 so p=0 always initializes
        unsigned bi = 0;
#pragma unroll
        for (int p = 0; p < PPT; ++p) {
            float dx = __fsub_rn(X[p], px);
            float dy = __fsub_rn(Y[p], py);
            float dz = __fsub_rn(Z[p], pz);
            float d  = __fadd_rn(__fadd_rn(__fmul_rn(dx, dx), __fmul_rn(dy, dy)),
                                 __fmul_rn(dz, dz));
            float m  = fminf(D[p], d);
            D[p] = m;
            if (m > bv) { bv = m; bi = g + (unsigned)p * GTHREADS; }  // strict > keeps first idx
        }
        unsigned long long best = packvi(bv, bi);

        // ---- wave reduce (64 lanes) ----
#pragma unroll
        for (int off = 32; off > 0; off >>= 1) {
            unsigned long long o = __shfl_down(best, off, 64);
            if (o > best) best = o;
        }

        // ---- block reduce via LDS ----
        if ((tid & 63u) == 0u) sred[tid >> 6] = best;
        __syncthreads();
        if (tid < 64u) {
            unsigned long long b2 = (tid < NWAVE) ? sred[tid] : 0ull;
#pragma unroll
            for (int off = NWAVE / 2; off > 0; off >>= 1) {
                unsigned long long o = __shfl_down(b2, off, 64);
                if (o > b2) b2 = o;
            }
            if (tid == 0u) {
                // Reset the slot that will be used at iteration i+1.
                // Safe: sits between barrier(i-1) and barrier(i); that slot's last
                // readers finished before barrier(i-1); its next writers start after barrier(i).
                if (blockIdx.x == 0)
                    __hip_atomic_store(&slots[(i + 1) % 3], 0ull,
                                       __ATOMIC_RELAXED, __HIP_MEMORY_SCOPE_AGENT);
                atomicMax(&slots[i % 3], b2);   // device-scope by default
            }
        }

        // ---- grid barrier (monotone counter, one arrive per block) ----
        __syncthreads();
        if (tid == 0u) {
            __hip_atomic_fetch_add(cnt, 1u, __ATOMIC_RELEASE, __HIP_MEMORY_SCOPE_AGENT);
            while (__hip_atomic_load(cnt, __ATOMIC_ACQUIRE, __HIP_MEMORY_SCOPE_AGENT) < target)
                __builtin_amdgcn_s_sleep(1);
            // Winner of this iteration; broadcast coords via LDS.
            unsigned long long w = __hip_atomic_load(&slots[i % 3],
                                                     __ATOMIC_RELAXED, __HIP_MEMORY_SCOPE_AGENT);
            unsigned widx = 0xFFFFFFFFu - (unsigned)(w & 0xFFFFFFFFull);
            float x = pos[3u * widx + 0];
            float y = pos[3u * widx + 1];
            float z = pos[3u * widx + 2];
            sx = x; sy = y; sz = z;
            if (blockIdx.x == 0) {
                out[3 * i + 0] = x; out[3 * i + 1] = y; out[3 * i + 2] = z;
            }
        }
        target += NBLK;
        __syncthreads();
        px = sx; py = sy; pz = sz;
    }
}

extern "C" void kernel_launch(void* const* d_in, const int* in_sizes, int n_in,
                              void* d_out, int out_size, void* d_ws, size_t ws_size,
                              hipStream_t stream) {
    const float* pos = (const float*)d_in[0];
    float* out = (float*)d_out;
    unsigned long long* slots = (unsigned long long*)d_ws;           // 3 x u64 at offset 0
    unsigned* cnt = (unsigned*)((char*)d_ws + 128);                  // own cache line

    // ws is poisoned 0xAA before every timed launch — zero our control block.
    hipMemsetAsync(d_ws, 0, 256, stream);

    void* args[] = { (void*)&pos, (void*)&out, (void*)&slots, (void*)&cnt };
    hipLaunchCooperativeKernel((void*)fps_kernel, dim3(NBLK), dim3(NTHR),
                               args, 0, stream);
}

// Round 2
// 5265.486 us; speedup vs baseline: 1.7051x; 1.7051x over previous
//
#include <hip/hip_runtime.h>
#include <float.h>

// FPS: N=524288 points, M=2048 selected (idx[0]=0), out = pos[idxs] (2048x3 f32).
// Persistent cooperative kernel. Per-iteration global argmax via DIRECT EXCHANGE:
// each block publishes a self-contained tagged 64-bit best to its own slot;
// every block's wave 0 polls all 64 slots (one lane each, relaxed agent loads)
// and reduces locally. One visibility hop per iteration instead of four.

#define NPTS     524288
#define MOUT     2048
#define NBLK     64
#define NTHR     512
#define NWAVE    (NTHR / 64)            // 8
#define GTHREADS (NBLK * NTHR)          // 32768
#define PPT      (NPTS / GTHREADS)      // 16
#define SLOT_STRIDE 8                   // u64 per slot -> 64 B, own cache line
#define MASK51   ((1ull << 51) - 1)

// packed word: [tag:13][fbits:32][idx_inv:19]
// fbits: IEEE bits of min_d (>=0 so bit order == value order)
// idx_inv = (NPTS-1) - idx: on equal fbits, larger idx_inv == smaller idx wins max
// => first-occurrence tie-break, matching jnp.argmax at every reduction level.

__global__ void __launch_bounds__(NTHR, 1) fps_kernel(
    const float* __restrict__ pos, float* __restrict__ out,
    unsigned long long* __restrict__ slots)
{
    const unsigned tid = threadIdx.x;
    const unsigned blk = blockIdx.x;
    const unsigned g   = blk * NTHR + tid;

    // Register-resident points + running min squared distance.
    float X[PPT], Y[PPT], Z[PPT], D[PPT];
#pragma unroll
    for (int p = 0; p < PPT; ++p) {
        const unsigned idx = g + (unsigned)p * GTHREADS;
        X[p] = pos[3u * idx + 0];
        Y[p] = pos[3u * idx + 1];
        Z[p] = pos[3u * idx + 2];
        D[p] = FLT_MAX;
    }

    float px = pos[0], py = pos[1], pz = pos[2];
    if (g == 0) { out[0] = px; out[1] = py; out[2] = pz; }

    __shared__ unsigned long long sred[NWAVE];
    __shared__ float sx, sy, sz;

    for (int i = 1; i < MOUT; ++i) {
        // ---- distance update + per-thread argmax (exact fp32: no FMA,
        // ---- sum order (dx^2+dy^2)+dz^2 — matches XLA elementwise+sum) ----
        float bv = -1.0f;
        unsigned bi = 0;
#pragma unroll
        for (int p = 0; p < PPT; ++p) {
            float dx = __fsub_rn(X[p], px);
            float dy = __fsub_rn(Y[p], py);
            float dz = __fsub_rn(Z[p], pz);
            float d  = __fadd_rn(__fadd_rn(__fmul_rn(dx, dx), __fmul_rn(dy, dy)),
                                 __fmul_rn(dz, dz));
            float m  = fminf(D[p], d);
            D[p] = m;
            if (m > bv) { bv = m; bi = g + (unsigned)p * GTHREADS; }
        }
        unsigned long long best =
            ((unsigned long long)__float_as_uint(bv) << 19) |
            (unsigned long long)((NPTS - 1u) - bi);

        // ---- wave reduce (64 lanes, 6 steps) ----
#pragma unroll
        for (int off = 32; off > 0; off >>= 1) {
            unsigned long long o = __shfl_down(best, off, 64);
            if (o > best) best = o;
        }
        if ((tid & 63u) == 0u) sred[tid >> 6] = best;
        __syncthreads();

        if (tid < 64u) {   // wave 0 only: finish block reduce, publish, poll, reduce
            unsigned long long b2 = (tid < NWAVE) ? sred[tid] : 0ull;
#pragma unroll
            for (int off = NWAVE / 2; off > 0; off >>= 1) {
                unsigned long long o = __shfl_down(b2, off, 64);
                if (o > b2) b2 = o;
            }
            unsigned long long* buf = slots + (unsigned)(i & 1) * (NBLK * SLOT_STRIDE);
            if (tid == 0u) {
                // publish this block's best: self-contained word, relaxed is enough
                __hip_atomic_store(&buf[blk * SLOT_STRIDE],
                                   ((unsigned long long)i << 51) | b2,
                                   __ATOMIC_RELAXED, __HIP_MEMORY_SCOPE_AGENT);
            }
            // every lane polls one block's slot (64 misses in flight in parallel)
            const unsigned long long tag = (unsigned long long)i;
            unsigned long long s;
            do {
                s = __hip_atomic_load(&buf[tid * SLOT_STRIDE],
                                      __ATOMIC_RELAXED, __HIP_MEMORY_SCOPE_AGENT);
                if ((s >> 51) == tag) break;
                __builtin_amdgcn_s_sleep(1);
            } while (true);
            unsigned long long v = s & MASK51;
#pragma unroll
            for (int off = 32; off > 0; off >>= 1) {
                unsigned long long o = __shfl_down(v, off, 64);
                if (o > v) v = o;
            }
            if (tid == 0u) {
                unsigned widx = (NPTS - 1u) - (unsigned)(v & 0x7FFFFull);
                float x = pos[3u * widx + 0];
                float y = pos[3u * widx + 1];
                float z = pos[3u * widx + 2];
                sx = x; sy = y; sz = z;
                if (blk == 0) {
                    out[3 * i + 0] = x; out[3 * i + 1] = y; out[3 * i + 2] = z;
                }
            }
        }
        __syncthreads();
        px = sx; py = sy; pz = sz;
    }
}

extern "C" void kernel_launch(void* const* d_in, const int* in_sizes, int n_in,
                              void* d_out, int out_size, void* d_ws, size_t ws_size,
                              hipStream_t stream) {
    const float* pos = (const float*)d_in[0];
    float* out = (float*)d_out;
    unsigned long long* slots = (unsigned long long*)d_ws;
    // No memset needed: 0xAA poison decodes to tag 0x1555, never equal to a
    // real iteration tag (1..2047); monotone tags + 2-buffer rotation kill ABA.

    void* args[] = { (void*)&pos, (void*)&out, (void*)&slots };
    hipLaunchCooperativeKernel((void*)fps_kernel, dim3(NBLK), dim3(NTHR),
                               args, 0, stream);
}